// Round 4
// baseline (7640.114 us; speedup 1.0000x reference)
//
#include <hip/hip_runtime.h>
#include <hip/hip_cooperative_groups.h>
#include <stdint.h>
#include <math.h>
#include <limits.h>

namespace cg = cooperative_groups;

// Batched autoregressive LSTM decode, B=32 S=48 V=32000 E=H=512.
// Round 3 (resubmit after broker timeout): single persistent cooperative
// kernel for all 48 steps. Per step: cell -> grid.sync -> MFMA logits
// (split-bf16) -> grid.sync -> redundant per-block finalize (each block
// reduces its own 4 batch rows). No per-block fences/atomics; coherence via
// the 2 grid syncs.

#define SEQ 48
#define BSZ 32
#define VOC 32000
#define EDIM 512
#define HDIM 512
#define GDIM 2048   // 4*H
#define KTOT 1024   // E + H
#define EOS_TOK (VOC - 2)
#define NBLK 250    // logits blocks (128 vocab each)

typedef __attribute__((ext_vector_type(8))) short bf16x8;
typedef __attribute__((ext_vector_type(4))) float f32x4;

__device__ __forceinline__ void threefry2x32(uint32_t k0, uint32_t k1,
                                             uint32_t x0, uint32_t x1,
                                             uint32_t& o0, uint32_t& o1)
{
  uint32_t ks2 = k0 ^ k1 ^ 0x1BD11BDAu;
  x0 += k0; x1 += k1;
#define TFR(r) x0 += x1; x1 = (x1 << (r)) | (x1 >> (32 - (r))); x1 ^= x0;
  TFR(13) TFR(15) TFR(26) TFR(6)
  x0 += k1; x1 += ks2 + 1u;
  TFR(17) TFR(29) TFR(16) TFR(24)
  x0 += ks2; x1 += k0 + 2u;
  TFR(13) TFR(15) TFR(26) TFR(6)
  x0 += k0; x1 += k1 + 3u;
  TFR(17) TFR(29) TFR(16) TFR(24)
  x0 += k1; x1 += ks2 + 4u;
  TFR(13) TFR(15) TFR(26) TFR(6)
  x0 += ks2; x1 += k0 + 5u;
#undef TFR
  o0 = x0; o1 = x1;
}

__device__ __forceinline__ uint32_t tf_bits(uint32_t k0, uint32_t k1, uint32_t m)
{
  // JAX partitionable threefry: 64-bit counter (hi=0, lo=m), draw = o0 ^ o1
  uint32_t o0, o1;
  threefry2x32(k0, k1, 0u, m, o0, o1);
  return o0 ^ o1;
}

__device__ __forceinline__ float gumbel_from_bits(uint32_t bits)
{
  uint32_t fb = (bits >> 9) | 0x3F800000u;
  float u = __uint_as_float(fb) - 1.0f;
  u = fmaxf(u, 1.1754943508222875e-38f);
  return -logf(-logf(u));
}

__device__ __forceinline__ float sigmoidf(float v) { return 1.0f / (1.0f + expf(-v)); }

__device__ __forceinline__ unsigned short f2bf(float f) {
  uint32_t u = __float_as_uint(f);
  uint32_t r = u + 0x7FFFu + ((u >> 16) & 1u);   // RNE
  return (unsigned short)(r >> 16);
}
__device__ __forceinline__ float bf2f(unsigned short h) {
  return __uint_as_float((uint32_t)h << 16);
}

// ---------------------------------------------------------------- transpose (cell weights)
// dst[(c + cOff)*dstLD + r] = src[r*C + c]
__global__ void transpose_kernel(const float* __restrict__ src, float* __restrict__ dst,
                                 int R, int C, int dstLD, int cOff)
{
  __shared__ float tile[32][33];
  int cb = blockIdx.x * 32, rb = blockIdx.y * 32;
  int tx = threadIdx.x, ty = threadIdx.y;
  for (int j = ty; j < 32; j += 8) {
    int r = rb + j, cc = cb + tx;
    if (r < R && cc < C) tile[j][tx] = src[(size_t)r * C + cc];
  }
  __syncthreads();
  for (int j = ty; j < 32; j += 8) {
    int r = rb + tx, cc = cb + j;
    if (r < R && cc < C) dst[(size_t)(cc + cOff) * dstLD + r] = tile[tx][j];
  }
}

// ---------------------------------------------------------------- weight frag pack
// Wo [32000][512] fp32 -> WP: frags [bid 250][ks 16][nt 8][plane 2][lane 64][8 bf16]
__global__ __launch_bounds__(256) void wprep_kernel(
    const float* __restrict__ Wo, unsigned short* __restrict__ WP)
{
  int i4 = blockIdx.x * 256 + threadIdx.x;       // one float4 per thread
  if (i4 >= VOC * 128) return;
  int v  = i4 >> 7;
  int k  = (i4 & 127) * 4;
  const float4 wv = ((const float4*)Wo)[i4];
  int bid  = v >> 7;
  int nt   = (v >> 4) & 7;
  int lane = (v & 15) + (((k >> 3) & 3) << 4);
  int ks   = k >> 5;
  int e0   = k & 7;                               // 0 or 4
  size_t f = (((size_t)bid * 16 + ks) * 8 + nt) * 2;
  size_t base = f * 512 + (size_t)lane * 8 + e0;
  unsigned short a0 = f2bf(wv.x), a1 = f2bf(wv.y), a2 = f2bf(wv.z), a3 = f2bf(wv.w);
  *(ushort4*)(WP + base)       = make_ushort4(a0, a1, a2, a3);
  *(ushort4*)(WP + base + 512) = make_ushort4(f2bf(wv.x - bf2f(a0)), f2bf(wv.y - bf2f(a1)),
                                              f2bf(wv.z - bf2f(a2)), f2bf(wv.w - bf2f(a3)));
}

// ---------------------------------------------------------------- persistent decode
__global__ __launch_bounds__(256, 1) void persist_kernel(
    const float* __restrict__ WT, const float* __restrict__ bi,
    const float* __restrict__ bh, const float* __restrict__ encoded,
    const float* __restrict__ emb, const bf16x8* __restrict__ WP,
    const float* __restrict__ bo, float* __restrict__ out,
    float* __restrict__ hA, float* __restrict__ hB,
    unsigned short* __restrict__ h1bf, unsigned short* __restrict__ h2bf,
    float* __restrict__ pmax, float* __restrict__ psum,
    float* __restrict__ pgv, int* __restrict__ pgi,
    float* __restrict__ lse_s, int* __restrict__ act_s)
{
  cg::grid_group grid = cg::this_grid();
  __shared__ __align__(16) char smem_raw[22016];
  __shared__ uint32_t keys_l[2 * SEQ];
  __shared__ int active_l[4], toks_l[4];

  const int t = threadIdx.x;
  const int blk = blockIdx.x;
  const int jc = blk & 31, bg = blk >> 5;
  const int bbase = bg * 4;

  if (t < SEQ) {
    uint32_t o0, o1;
    threefry2x32(0u, 42u, 0u, (uint32_t)t, o0, o1);
    keys_l[2 * t] = o0; keys_l[2 * t + 1] = o1;
  }
  if (t < 4) active_l[t] = 1;
  __syncthreads();

  float c_reg = 0.f;                       // cell state (threads t<64 only)
  float* hprev = hA;
  float* hcur  = hB;

  for (int sp = 0; sp < SEQ; ++sp) {
    // ================= phase A: LSTM cell =================
    {
      float* xh   = (float*)smem_raw;      // [1024][4b] 16KB
      float* red  = xh + 4096;             // [4][64][4b] 4KB
      float* gate = red + 1024;            // [64][4b]    1KB

      for (int i = 0; i < 16; ++i) {
        int bb = i >> 2;
        int k = (i & 3) * 256 + t;
        float v;
        if (k < EDIM) {
          v = (sp == 0) ? encoded[(bbase + bb) * EDIM + k]
                        : emb[(size_t)toks_l[bb] * EDIM + k];
        } else {
          v = (sp == 0) ? 0.f : hprev[(bbase + bb) * HDIM + (k - EDIM)];
        }
        xh[k * 4 + bb] = v;
      }
      __syncthreads();

      {
        int gl = t & 63, kq = t >> 6;
        int type = gl >> 4, jj = gl & 15;
        int gcol = type * 512 + jc * 16 + jj;
        float acc0 = 0.f, acc1 = 0.f, acc2 = 0.f, acc3 = 0.f;
        const float* wp = WT + (size_t)(kq * 256) * GDIM + gcol;
        const float4* xp = (const float4*)xh + kq * 256;
#pragma unroll 8
        for (int k = 0; k < 256; ++k) {
          float w = wp[(size_t)k * GDIM];
          float4 h4 = xp[k];
          acc0 += w * h4.x; acc1 += w * h4.y; acc2 += w * h4.z; acc3 += w * h4.w;
        }
        ((float4*)red)[t] = make_float4(acc0, acc1, acc2, acc3);
      }
      __syncthreads();

      if (t < 64) {
        float4 s0 = ((float4*)red)[t];
        float4 s1 = ((float4*)red)[64 + t];
        float4 s2 = ((float4*)red)[128 + t];
        float4 s3 = ((float4*)red)[192 + t];
        int ty2 = t >> 4, jj2 = t & 15;
        int gc2 = ty2 * 512 + jc * 16 + jj2;
        float bsum = bi[gc2] + bh[gc2];
        float4 g;
        g.x = s0.x + s1.x + s2.x + s3.x + bsum;
        g.y = s0.y + s1.y + s2.y + s3.y + bsum;
        g.z = s0.z + s1.z + s2.z + s3.z + bsum;
        g.w = s0.w + s1.w + s2.w + s3.w + bsum;
        ((float4*)gate)[t] = g;
      }
      __syncthreads();

      if (t < 64) {
        int bb = t >> 4, jjf = t & 15;
        float ig = sigmoidf(gate[(0 * 16 + jjf) * 4 + bb]);
        float fg = sigmoidf(gate[(1 * 16 + jjf) * 4 + bb]);
        float gg = tanhf(  gate[(2 * 16 + jjf) * 4 + bb]);
        float og = sigmoidf(gate[(3 * 16 + jjf) * 4 + bb]);
        float cn = fg * c_reg + ig * gg;
        c_reg = cn;
        float hv = og * tanhf(cn);
        int ci = (bbase + bb) * HDIM + jc * 16 + jjf;
        hcur[ci] = hv;
        unsigned short hh = f2bf(hv);
        h1bf[ci] = hh;
        h2bf[ci] = f2bf(hv - bf2f(hh));
      }
    }
    grid.sync();

    // ================= phase B: MFMA logits =================
    if (blk < NBLK) {
      float* cmf = (float*)smem_raw;       // [4][32]
      float* csf = cmf + 128;
      float* cvf = csf + 128;
      int*   cif = (int*)(cvf + 128);

      const bf16x8* h1v = (const bf16x8*)h1bf;
      const bf16x8* h2v = (const bf16x8*)h2bf;
      const int w = t >> 6, l = t & 63;
      const int lr = l & 15, lq = l >> 4;
      const int v0 = blk * 128;

      f32x4 a00 = {0.f, 0.f, 0.f, 0.f};
      f32x4 a01 = a00, a10 = a00, a11 = a00;

      const int ab0 = lr * 64 + lq;
      const int ab1 = (16 + lr) * 64 + lq;
      const int wb0 = blk * 16384 + (w * 2) * 128 + l;

#pragma unroll 2
      for (int ks = 0; ks < 16; ++ks) {
        bf16x8 x10 = h1v[ab0 + ks * 4];
        bf16x8 x11 = h1v[ab1 + ks * 4];
        bf16x8 x20 = h2v[ab0 + ks * 4];
        bf16x8 x21 = h2v[ab1 + ks * 4];
        const int wb = wb0 + ks * 1024;
        bf16x8 w10 = WP[wb];
        bf16x8 w20 = WP[wb + 64];
        bf16x8 w11 = WP[wb + 128];
        bf16x8 w21 = WP[wb + 192];
        a00 = __builtin_amdgcn_mfma_f32_16x16x32_bf16(x10, w10, a00, 0, 0, 0);
        a01 = __builtin_amdgcn_mfma_f32_16x16x32_bf16(x10, w11, a01, 0, 0, 0);
        a10 = __builtin_amdgcn_mfma_f32_16x16x32_bf16(x11, w10, a10, 0, 0, 0);
        a11 = __builtin_amdgcn_mfma_f32_16x16x32_bf16(x11, w11, a11, 0, 0, 0);
        a00 = __builtin_amdgcn_mfma_f32_16x16x32_bf16(x10, w20, a00, 0, 0, 0);
        a01 = __builtin_amdgcn_mfma_f32_16x16x32_bf16(x10, w21, a01, 0, 0, 0);
        a10 = __builtin_amdgcn_mfma_f32_16x16x32_bf16(x11, w20, a10, 0, 0, 0);
        a11 = __builtin_amdgcn_mfma_f32_16x16x32_bf16(x11, w21, a11, 0, 0, 0);
        a00 = __builtin_amdgcn_mfma_f32_16x16x32_bf16(x20, w10, a00, 0, 0, 0);
        a01 = __builtin_amdgcn_mfma_f32_16x16x32_bf16(x20, w11, a01, 0, 0, 0);
        a10 = __builtin_amdgcn_mfma_f32_16x16x32_bf16(x21, w10, a10, 0, 0, 0);
        a11 = __builtin_amdgcn_mfma_f32_16x16x32_bf16(x21, w11, a11, 0, 0, 0);
      }

      const int va = v0 + w * 32 + lr;
      const int vb = va + 16;
      const float boa = bo[va], bob = bo[vb];
      const uint32_t k0 = keys_l[2 * sp], k1 = keys_l[2 * sp + 1];

#pragma unroll
      for (int mt = 0; mt < 2; ++mt) {
        const f32x4 A0 = mt ? a10 : a00;
        const f32x4 A1 = mt ? a11 : a01;
#pragma unroll
        for (int reg = 0; reg < 4; ++reg) {
          const int b = mt * 16 + lq * 4 + reg;
          const float La = A0[reg] + boa;
          const float Lb = A1[reg] + bob;
          size_t obase = (size_t)b * (SEQ * VOC) + (size_t)sp * VOC;
          out[obase + va] = La;
          out[obase + vb] = Lb;

          float mx = fmaxf(La, Lb);
          mx = fmaxf(mx, __shfl_xor(mx, 1, 64));
          mx = fmaxf(mx, __shfl_xor(mx, 2, 64));
          mx = fmaxf(mx, __shfl_xor(mx, 4, 64));
          mx = fmaxf(mx, __shfl_xor(mx, 8, 64));
          float se = expf(La - mx) + expf(Lb - mx);

          uint32_t ba = tf_bits(k0, k1, (uint32_t)(b * VOC + va));
          uint32_t bb2 = tf_bits(k0, k1, (uint32_t)(b * VOC + vb));
          float ga = La + gumbel_from_bits(ba);
          float gb = Lb + gumbel_from_bits(bb2);
          float gvx; int gix;
          if (ga >= gb) { gvx = ga; gix = va; } else { gvx = gb; gix = vb; }
#pragma unroll
          for (int d = 1; d < 16; d <<= 1) {
            se += __shfl_xor(se, d, 64);
            float og = __shfl_xor(gvx, d, 64);
            int   oi = __shfl_xor(gix, d, 64);
            if (og > gvx || (og == gvx && oi < gix)) { gvx = og; gix = oi; }
          }
          if (lr == 0) {
            cmf[w * 32 + b] = mx; csf[w * 32 + b] = se;
            cvf[w * 32 + b] = gvx; cif[w * 32 + b] = gix;
          }
        }
      }
      __syncthreads();

      if (t < 32) {
        const int b = t;
        float M = cmf[b];
        M = fmaxf(M, cmf[32 + b]); M = fmaxf(M, cmf[64 + b]); M = fmaxf(M, cmf[96 + b]);
        float S = 0.f;
        float GV = -INFINITY; int GI = INT_MAX;
#pragma unroll
        for (int ww = 0; ww < 4; ++ww) {
          S += csf[ww * 32 + b] * expf(cmf[ww * 32 + b] - M);
          if (cvf[ww * 32 + b] > GV ||
              (cvf[ww * 32 + b] == GV && cif[ww * 32 + b] < GI)) {
            GV = cvf[ww * 32 + b]; GI = cif[ww * 32 + b];
          }
        }
        pmax[blk * 32 + b] = M;
        psum[blk * 32 + b] = S;
        pgv[blk * 32 + b]  = GV;
        pgi[blk * 32 + b]  = GI;
      }
    }
    grid.sync();

    // ================= phase C: finalize (redundant, own 4 batch rows) =====
    {
      float* Lm = (float*)smem_raw;        // [1000] (padded 1024)
      float* Ls = Lm + 1024;
      float* Lv = Ls + 1024;
      int*   Li = (int*)(Lv + 1024);
      float* Cm = (float*)(Li + 1024);     // [256]
      float* Cs = Cm + 256;
      float* Cv = Cs + 256;
      int*   Ci = (int*)(Cv + 256);

      for (int i = t; i < NBLK * 4; i += 256) {
        int pb = i >> 2, bl = i & 3;
        Lm[i] = pmax[pb * 32 + bbase + bl];
        Ls[i] = psum[pb * 32 + bbase + bl];
        Lv[i] = pgv[pb * 32 + bbase + bl];
        Li[i] = pgi[pb * 32 + bbase + bl];
      }
      __syncthreads();
      {
        int bl = t & 3, j = t >> 2;        // 64 chunks per b
        float M = -INFINITY, S = 0.f, GV = -INFINITY; int GI = INT_MAX;
        for (int i = j; i < NBLK; i += 64) {
          int idx = i * 4 + bl;
          float m = Lm[idx], sv = Ls[idx], g = Lv[idx]; int gi = Li[idx];
          float mn = fmaxf(M, m);
          S = S * expf(M - mn) + sv * expf(m - mn);
          M = mn;
          if (g > GV || (g == GV && gi < GI)) { GV = g; GI = gi; }
        }
        Cm[t] = M; Cs[t] = S; Cv[t] = GV; Ci[t] = GI;
      }
      __syncthreads();
      if (t < 4) {
        float M = Cm[t], S = Cs[t], GV = Cv[t]; int GI = Ci[t];
        for (int j = 1; j < 64; ++j) {
          int idx = j * 4 + t;
          float m = Cm[idx];
          float mn = fmaxf(M, m);
          S = S * expf(M - mn) + Cs[idx] * expf(m - mn);
          M = mn;
          if (Cv[idx] > GV || (Cv[idx] == GV && Ci[idx] < GI)) {
            GV = Cv[idx]; GI = Ci[idx];
          }
        }
        int bglob = bbase + t;
        if (jc == 0) {
          lse_s[sp * 32 + bglob] = M + logf(S);
          act_s[sp * 32 + bglob] = active_l[t];
        }
        toks_l[t] = GI;
        if (GI == EOS_TOK) active_l[t] = 0;
      }
      __syncthreads();
    }

    float* tmp = hprev; hprev = hcur; hcur = tmp;
  }
}

// ---------------------------------------------------------------- epilogue
__global__ __launch_bounds__(256) void finish_kernel(
    float4* __restrict__ out4, const float* __restrict__ lse_s,
    const int* __restrict__ act_s)
{
  const int N4 = BSZ * SEQ * VOC / 4;
  for (int f = blockIdx.x * 256 + threadIdx.x; f < N4; f += gridDim.x * 256) {
    int row = f / (VOC / 4);
    int b = row / SEQ, s = row - b * SEQ;
    int idx = s * 32 + b;
    float4 v = out4[f];
    if (act_s[idx]) {
      float lsv = lse_s[idx];
      v.x -= lsv; v.y -= lsv; v.z -= lsv; v.w -= lsv;
    } else {
      v.x = 0.f; v.y = 0.f; v.z = 0.f; v.w = 0.f;
    }
    out4[f] = v;
  }
}

// ---------------------------------------------------------------- launch
extern "C" void kernel_launch(void* const* d_in, const int* in_sizes, int n_in,
                              void* d_out, int out_size, void* d_ws, size_t ws_size,
                              hipStream_t stream)
{
  (void)in_sizes; (void)n_in; (void)out_size; (void)ws_size;
  const float* encoded = (const float*)d_in[0];
  const float* emb     = (const float*)d_in[1];
  const float* Wi      = (const float*)d_in[2];
  const float* Wh      = (const float*)d_in[3];
  const float* bi      = (const float*)d_in[4];
  const float* bh      = (const float*)d_in[5];
  const float* Wo      = (const float*)d_in[6];
  const float* bo      = (const float*)d_in[7];
  float* out = (float*)d_out;

  char* W = (char*)d_ws;
  size_t off = 0;
  float* WT = (float*)(W + off);            off += (size_t)KTOT * GDIM * 4;        // 8 MB
  unsigned short* WPu = (unsigned short*)(W + off); off += (size_t)VOC * 512 * 2 * 2; // 65.5 MB
  float* hA = (float*)(W + off);            off += BSZ * HDIM * 4;
  float* hB = (float*)(W + off);            off += BSZ * HDIM * 4;
  unsigned short* h1bf = (unsigned short*)(W + off); off += BSZ * HDIM * 2;
  unsigned short* h2bf = (unsigned short*)(W + off); off += BSZ * HDIM * 2;
  float* pmax = (float*)(W + off);          off += NBLK * 32 * 4;
  float* psum = (float*)(W + off);          off += NBLK * 32 * 4;
  float* pgv  = (float*)(W + off);          off += NBLK * 32 * 4;
  int*   pgi  = (int*)(W + off);            off += NBLK * 32 * 4;
  float* lse_s = (float*)(W + off);         off += SEQ * BSZ * 4;
  int*   act_s = (int*)(W + off);           off += SEQ * BSZ * 4;

  transpose_kernel<<<dim3(16, 64), dim3(32, 8), 0, stream>>>(Wi, WT, GDIM, EDIM, GDIM, 0);
  transpose_kernel<<<dim3(16, 64), dim3(32, 8), 0, stream>>>(Wh, WT, GDIM, HDIM, GDIM, 512);
  wprep_kernel<<<dim3((VOC * 128 + 255) / 256), dim3(256), 0, stream>>>(Wo, WPu);

  const bf16x8* WP = (const bf16x8*)WPu;
  void* args[] = {
    (void*)&WT, (void*)&bi, (void*)&bh, (void*)&encoded, (void*)&emb,
    (void*)&WP, (void*)&bo, (void*)&out, (void*)&hA, (void*)&hB,
    (void*)&h1bf, (void*)&h2bf, (void*)&pmax, (void*)&psum,
    (void*)&pgv, (void*)&pgi, (void*)&lse_s, (void*)&act_s
  };
  hipLaunchCooperativeKernel((const void*)persist_kernel, dim3(256), dim3(256),
                             args, 0, stream);

  finish_kernel<<<dim3(2048), dim3(256), 0, stream>>>((float4*)out, lse_s, act_s);
}